// Round 7
// baseline (971.445 us; speedup 1.0000x reference)
//
#include <hip/hip_runtime.h>
#include <math.h>

// Problem constants
#define NROWS 16384       // 8*2048
#define DIN   1024
#define DBN   256
#define NQ    8
#define NCODE 1024
#define MARGIN 2.0f

// Output layout (float32 flat)
#define OFF_Z    0
#define OFF_Q    4194304
#define OFF_IDX  8388608
#define OFF_REC  8519680
#define OFF_COM  25296896

typedef __attribute__((ext_vector_type(8))) short short8v;
typedef __attribute__((ext_vector_type(4))) float f32x4;

__device__ __forceinline__ float gelu_f(float x) {
  return 0.5f * x * (1.0f + erff(x * 0.70710678118654752440f));
}

__device__ __forceinline__ ushort f2b(float x) {
  unsigned u = __float_as_uint(x);
  unsigned r = u + 0x7FFF + ((u >> 16) & 1);
  return (ushort)(r >> 16);
}
__device__ __forceinline__ float b2f(ushort u) {
  return __uint_as_float((unsigned)u << 16);
}
// 3-way bf16 split, ROUND-to-nearest at every stage (R4/R6-proven):
// v = b1 + b2 + b3 + err, |err| <= ~2^-24 |v|. Truncating variants (R5,
// ~2^-22) flip near-tie argmins — NEVER weaken this.
__device__ __forceinline__ void split3(float v, ushort& s1, ushort& s2, ushort& s3) {
  s1 = f2b(v);
  const float r1 = v - b2f(s1);
  s2 = f2b(r1);
  const float r2 = r1 - b2f(s2);
  s3 = f2b(r2);
}

// ---------------------------------------------------------------------------
// fp32-accurate GEMM on MFMA via 3-way bf16 split (6 products):
// C = act(A@B^T + bias). 128xBN tile (BN=NB*32), BK=32, 4 waves (2x2).
// R7: A never touches LDS — each wave loads its fragment rows directly from
// global (fp32) and splits in registers (bit-identical to LDS round-trip).
// LDS holds only B (rows of 192B: part p at row*192+p*64+2k, XOR (row&7)<<4;
// both the row-per-lane writes and the fragment reads hit 8 distinct 16B
// granules per 8-lane group = conflict-free). LDS ops/wave-iter: 36 -> 18.
// OUT=0: write C0 fp32. OUT=1: write C0, C1 fp32 + Ob bf16.
// ---------------------------------------------------------------------------
template<bool GELU, int NB, int OUT>
__global__ __launch_bounds__(256) void gemm6(
    const float* __restrict__ Af,
    const ushort* __restrict__ B1, const ushort* __restrict__ B2,
    const ushort* __restrict__ B3,
    const float* __restrict__ bias,
    float* __restrict__ C0, float* __restrict__ C1, ushort* __restrict__ Ob,
    int N, int K)
{
  constexpr int BN = NB * 32;
  __shared__ char ldsB[BN * 192];
  const int tid = threadIdx.x;
  const int bm = blockIdx.x * 128;
  const int bn = blockIdx.y * BN;
  const int lane = tid & 63;
  const int wid = tid >> 6;
  const int wr = wid >> 1, wc = wid & 1;

  // A-direct fragment pointers: lane l covers A[frag_row + (l&15)][(l>>4)*8 ..+8]
  const float* Am[4];
  #pragma unroll
  for (int m = 0; m < 4; ++m)
    Am[m] = Af + (size_t)(bm + wr * 64 + m * 16 + (lane & 15)) * K + (lane >> 4) * 8;

  // B staging: one row per thread-slot (adjacent lanes -> distinct rows ->
  // distinct granules under the XOR swizzle; conflict-free writes).
  const int brow = tid & (BN - 1);
  const int bsel = (NB == 4) ? (tid >> 7) : (tid >> 6);
  const int bkoff = bsel * (NB == 4 ? 16 : 8);          // ushort offset in row
  const ushort* Bp1 = B1 + (size_t)(bn + brow) * K + bkoff;
  const ushort* Bp2 = B2 + (size_t)(bn + brow) * K + bkoff;
  const ushort* Bp3 = B3 + (size_t)(bn + brow) * K + bkoff;
  const int bswz = (brow & 7) << 4;
  const int bb0 = brow * 192 + 2 * bkoff;

  f32x4 acc[4][NB];
  #pragma unroll
  for (int m = 0; m < 4; ++m)
    #pragma unroll
    for (int n = 0; n < NB; ++n) acc[m][n] = (f32x4)0.f;

  union U8 { ushort u[8]; short8v v; };

  const int nt = K >> 5;
  for (int t = 0; t < nt; ++t) {
    const int k0 = t << 5;
    // A fragment loads (global fp32, L1/L2-cached) — issue before the barrier
    float av[4][8];
    #pragma unroll
    for (int m = 0; m < 4; ++m) {
      *(float4*)&av[m][0] = *(const float4*)(Am[m] + k0);
      *(float4*)&av[m][4] = *(const float4*)(Am[m] + k0 + 4);
    }
    __syncthreads();          // previous-iter B reads complete
    // B staging: pre-split bf16 parts -> LDS
    if (NB == 4) {
      #pragma unroll
      for (int h2 = 0; h2 < 2; ++h2) {
        *(uint4*)(ldsB + ((bb0 + 0   + h2 * 16) ^ bswz)) = *(const uint4*)(Bp1 + k0 + h2 * 8);
        *(uint4*)(ldsB + ((bb0 + 64  + h2 * 16) ^ bswz)) = *(const uint4*)(Bp2 + k0 + h2 * 8);
        *(uint4*)(ldsB + ((bb0 + 128 + h2 * 16) ^ bswz)) = *(const uint4*)(Bp3 + k0 + h2 * 8);
      }
    } else {
      *(uint4*)(ldsB + ((bb0 + 0  ) ^ bswz)) = *(const uint4*)(Bp1 + k0);
      *(uint4*)(ldsB + ((bb0 + 64 ) ^ bswz)) = *(const uint4*)(Bp2 + k0);
      *(uint4*)(ldsB + ((bb0 + 128) ^ bswz)) = *(const uint4*)(Bp3 + k0);
    }
    // split A in registers while B-staging stores land (VALU ∥ memory)
    U8 a1[4], a2[4], a3[4];
    #pragma unroll
    for (int m = 0; m < 4; ++m)
      #pragma unroll
      for (int i = 0; i < 8; ++i)
        split3(av[m][i], a1[m].u[i], a2[m].u[i], a3[m].u[i]);
    __syncthreads();          // B tile visible
    const int kq = (lane >> 4) << 4;
    #pragma unroll
    for (int n = 0; n < NB; ++n) {
      const int rowb = wc * (NB * 16) + n * 16 + (lane & 15);
      const int base = rowb * 192, swz = (rowb & 7) << 4;
      const short8v b1 = *(const short8v*)(ldsB + ((base + 0   + kq) ^ swz));
      const short8v b2 = *(const short8v*)(ldsB + ((base + 64  + kq) ^ swz));
      const short8v b3 = *(const short8v*)(ldsB + ((base + 128 + kq) ^ swz));
      #pragma unroll
      for (int m = 0; m < 4; ++m) {
        f32x4 a = acc[m][n];
        a = __builtin_amdgcn_mfma_f32_16x16x32_bf16(a3[m].v, b1, a, 0, 0, 0);
        a = __builtin_amdgcn_mfma_f32_16x16x32_bf16(a1[m].v, b3, a, 0, 0, 0);
        a = __builtin_amdgcn_mfma_f32_16x16x32_bf16(a2[m].v, b2, a, 0, 0, 0);
        a = __builtin_amdgcn_mfma_f32_16x16x32_bf16(a2[m].v, b1, a, 0, 0, 0);
        a = __builtin_amdgcn_mfma_f32_16x16x32_bf16(a1[m].v, b2, a, 0, 0, 0);
        a = __builtin_amdgcn_mfma_f32_16x16x32_bf16(a1[m].v, b1, a, 0, 0, 0);
        acc[m][n] = a;
      }
    }
  }

  #pragma unroll
  for (int n = 0; n < NB; ++n) {
    const int col = bn + wc * (NB * 16) + n * 16 + (lane & 15);
    const float bb = bias[col];
    #pragma unroll
    for (int m = 0; m < 4; ++m) {
      const int row0 = bm + wr * 64 + m * 16 + ((lane >> 4) << 2);
      #pragma unroll
      for (int r = 0; r < 4; ++r) {
        float v = acc[m][n][r] + bb;
        if (GELU) v = gelu_f(v);
        C0[(size_t)(row0 + r) * N + col] = v;
        if (OUT == 1) {
          C1[(size_t)(row0 + r) * N + col] = v;
          Ob[(size_t)(row0 + r) * N + col] = f2b(v);
        }
      }
    }
  }
}

// ---------------------------------------------------------------------------
// bf16 MFMA GEMM core (screen + decoder): 128x128 tile, BK=64, 4 waves.
// A [M][K] bf16 row-major, B [N][K] bf16 (transposed). XOR-swizzled LDS.
// ---------------------------------------------------------------------------
__device__ __forceinline__ void mm_core(
    const ushort* __restrict__ A, const ushort* __restrict__ B,
    int K, int bm, int bn, char* lds, f32x4 acc[4][4])
{
  char* ldsA = lds;
  char* ldsB = lds + 16384;
  const int tid = threadIdx.x;
  const int lane = tid & 63;
  const int wid = tid >> 6;
  const int wr = wid >> 1, wc = wid & 1;

  #pragma unroll
  for (int m = 0; m < 4; ++m)
    #pragma unroll
    for (int n = 0; n < 4; ++n) acc[m][n] = (f32x4)0.f;

  const int nt = K >> 6;
  for (int t = 0; t < nt; ++t) {
    const int k0 = t << 6;
    __syncthreads();
    #pragma unroll
    for (int c = 0; c < 4; ++c) {
      const int id = c * 256 + tid;
      const int row = id >> 3, k8 = id & 7;
      const uint4 va = *(const uint4*)(A + (size_t)(bm + row) * K + k0 + k8 * 8);
      const uint4 vb = *(const uint4*)(B + (size_t)(bn + row) * K + k0 + k8 * 8);
      const int off = (row * 128 + k8 * 16) ^ ((row & 7) << 4);
      *(uint4*)(ldsA + off) = va;
      *(uint4*)(ldsB + off) = vb;
    }
    __syncthreads();
    #pragma unroll
    for (int kk = 0; kk < 2; ++kk) {
      short8v af[4], bfr[4];
      #pragma unroll
      for (int m = 0; m < 4; ++m) {
        const int row = wr * 64 + m * 16 + (lane & 15);
        af[m] = *(const short8v*)(ldsA +
            ((row * 128 + kk * 64 + ((lane >> 4) << 4)) ^ ((row & 7) << 4)));
      }
      #pragma unroll
      for (int n = 0; n < 4; ++n) {
        const int row = wc * 64 + n * 16 + (lane & 15);
        bfr[n] = *(const short8v*)(ldsB +
            ((row * 128 + kk * 64 + ((lane >> 4) << 4)) ^ ((row & 7) << 4)));
      }
      #pragma unroll
      for (int m = 0; m < 4; ++m)
        #pragma unroll
        for (int n = 0; n < 4; ++n)
          acc[m][n] = __builtin_amdgcn_mfma_f32_16x16x32_bf16(
              af[m], bfr[n], acc[m][n], 0, 0, 0);
    }
  }
}

// RVQ screen: approx d2 = cnorm - 2*(res.c) in bf16 MFMA -> fp16 matrix D.
__global__ __launch_bounds__(256) void rvq_screen(
    const ushort* __restrict__ resb, const ushort* __restrict__ cbb,
    const float* __restrict__ cnorm, _Float16* __restrict__ D)
{
  __shared__ char lds[32768];
  f32x4 acc[4][4];
  const int bm = blockIdx.x * 128, bn = blockIdx.y * 128;
  mm_core(resb, cbb, DBN, bm, bn, lds, acc);
  const int lane = threadIdx.x & 63;
  const int wid = threadIdx.x >> 6;
  const int wr = wid >> 1, wc = wid & 1;
  #pragma unroll
  for (int n = 0; n < 4; ++n) {
    const int col = bn + wc * 64 + n * 16 + (lane & 15);
    const float cn = cnorm[col];
    #pragma unroll
    for (int m = 0; m < 4; ++m) {
      const int row0 = bm + wr * 64 + m * 16 + ((lane >> 4) << 2);
      #pragma unroll
      for (int r = 0; r < 4; ++r)
        D[(size_t)(row0 + r) * NCODE + col] = (_Float16)(cn - 2.0f * acc[m][n][r]);
    }
  }
}

// Decoder bf16 GEMM: C = act(A@Bt^T + bias); fp32 or bf16 output.
template<bool GELU, bool OUTF>
__global__ __launch_bounds__(256) void gemm_bf16(
    const ushort* __restrict__ A, const ushort* __restrict__ Bt,
    const float* __restrict__ bias, float* __restrict__ Cf,
    ushort* __restrict__ Cb, int N, int K)
{
  __shared__ char lds[32768];
  f32x4 acc[4][4];
  const int bm = blockIdx.x * 128, bn = blockIdx.y * 128;
  mm_core(A, Bt, K, bm, bn, lds, acc);
  const int lane = threadIdx.x & 63;
  const int wid = threadIdx.x >> 6;
  const int wr = wid >> 1, wc = wid & 1;
  #pragma unroll
  for (int n = 0; n < 4; ++n) {
    const int col = bn + wc * 64 + n * 16 + (lane & 15);
    const float bb = bias[col];
    #pragma unroll
    for (int m = 0; m < 4; ++m) {
      const int row0 = bm + wr * 64 + m * 16 + ((lane >> 4) << 2);
      #pragma unroll
      for (int r = 0; r < 4; ++r) {
        float v = acc[m][n][r] + bb;
        if (GELU) v = gelu_f(v);
        if (OUTF) Cf[(size_t)(row0 + r) * N + col] = v;
        else      Cb[(size_t)(row0 + r) * N + col] = f2b(v);
      }
    }
  }
}

// Codebook squared norms (exact fp32): one wave per code row.
__global__ __launch_bounds__(256) void cnorm_kernel(
    const float* __restrict__ cb, float* __restrict__ cnorm)
{
  const int code = blockIdx.x * 4 + (threadIdx.x >> 6);
  const int lane = threadIdx.x & 63;
  float4 v = *(const float4*)(cb + (size_t)code * DBN + lane * 4);
  float s = v.x * v.x + v.y * v.y + v.z * v.z + v.w * v.w;
  #pragma unroll
  for (int o = 32; o > 0; o >>= 1) s += __shfl_down(s, o, 64);
  if (lane == 0) cnorm[code] = s;
}

// ---------------------------------------------------------------------------
// RVQ rescore + finalize (one wave per row): candidates within MARGIN of the
// approx min, exact fp32 rescore (lowest-index tie-break), residual update.
// ---------------------------------------------------------------------------
__global__ __launch_bounds__(256) void rvq_rescore(
    const _Float16* __restrict__ D, const float* __restrict__ cb_s,
    const float* __restrict__ cnorm_s,
    float* __restrict__ res, ushort* __restrict__ resb,
    float* __restrict__ idx_out, float* __restrict__ closs_part)
{
  __shared__ int cnt[4];
  __shared__ ushort cand[4][128];
  __shared__ float wsum[4];
  const int w = threadIdx.x >> 6, lane = threadIdx.x & 63;
  const int row = blockIdx.x * 4 + w;
  if (lane == 0) cnt[w] = 0;

  union H8 { uint4 u; _Float16 h[8]; };
  const _Float16* Dr = D + (size_t)row * NCODE + lane * 16;
  H8 a0, a1;
  a0.u = *(const uint4*)(Dr);
  a1.u = *(const uint4*)(Dr + 8);
  float dv[16];
  #pragma unroll
  for (int i = 0; i < 8; ++i) { dv[i] = (float)a0.h[i]; dv[8 + i] = (float)a1.h[i]; }

  float mn = dv[0];
  #pragma unroll
  for (int i = 1; i < 16; ++i) mn = fminf(mn, dv[i]);
  #pragma unroll
  for (int o = 32; o > 0; o >>= 1) mn = fminf(mn, __shfl_xor(mn, o, 64));
  const float thr = mn + MARGIN;

  #pragma unroll
  for (int i = 0; i < 16; ++i)
    if (dv[i] < thr) {
      int p = atomicAdd(&cnt[w], 1);
      if (p < 128) cand[w][p] = (ushort)(lane * 16 + i);
    }
  const int ncand = min(cnt[w], 128);

  const float4 r4 = *(const float4*)(res + (size_t)row * DBN + lane * 4);
  float bestv = INFINITY; int besti = 0x7fffffff;
  for (int c = 0; c < ncand; ++c) {
    const int code = cand[w][c];
    const float4 c4 = *(const float4*)(cb_s + (size_t)code * DBN + lane * 4);
    float d = r4.x * c4.x + r4.y * c4.y + r4.z * c4.z + r4.w * c4.w;
    #pragma unroll
    for (int o = 32; o > 0; o >>= 1) d += __shfl_xor(d, o, 64);
    const float ex = cnorm_s[code] - 2.0f * d;
    if (ex < bestv || (ex == bestv && code < besti)) { bestv = ex; besti = code; }
  }

  const float4 q4 = *(const float4*)(cb_s + (size_t)besti * DBN + lane * 4);
  float4 n4;
  n4.x = r4.x - q4.x; n4.y = r4.y - q4.y; n4.z = r4.z - q4.z; n4.w = r4.w - q4.w;
  *(float4*)(res + (size_t)row * DBN + lane * 4) = n4;
  ushort4 nb;
  nb.x = f2b(n4.x); nb.y = f2b(n4.y); nb.z = f2b(n4.z); nb.w = f2b(n4.w);
  *(ushort4*)(resb + (size_t)row * DBN + lane * 4) = nb;

  float s = n4.x * n4.x + n4.y * n4.y + n4.z * n4.z + n4.w * n4.w;
  #pragma unroll
  for (int o = 32; o > 0; o >>= 1) s += __shfl_xor(s, o, 64);
  if (lane == 0) { wsum[w] = s; idx_out[row] = (float)besti; }
  __syncthreads();
  if (threadIdx.x == 0)
    closs_part[blockIdx.x] = wsum[0] + wsum[1] + wsum[2] + wsum[3];
}

// q_total gather + straight-through: q = z + (sum_s cb[s][idx_s] - z).
__global__ __launch_bounds__(256) void qfix_gather(
    const float* __restrict__ z, const float* __restrict__ idxf,
    const float* __restrict__ cb, float* __restrict__ q, ushort* __restrict__ qb)
{
  const int w = threadIdx.x >> 6, lane = threadIdx.x & 63;
  const int row = blockIdx.x * 4 + w;
  float4 a; a.x = 0.f; a.y = 0.f; a.z = 0.f; a.w = 0.f;
  #pragma unroll
  for (int s = 0; s < NQ; ++s) {
    const int ix = (int)idxf[(size_t)s * NROWS + row];
    const float4 c4 = *(const float4*)(cb + ((size_t)s * NCODE + ix) * DBN + lane * 4);
    a.x += c4.x; a.y += c4.y; a.z += c4.z; a.w += c4.w;
  }
  const float4 z4 = *(const float4*)(z + (size_t)row * DBN + lane * 4);
  float4 qv;
  qv.x = z4.x + (a.x - z4.x); qv.y = z4.y + (a.y - z4.y);
  qv.z = z4.z + (a.z - z4.z); qv.w = z4.w + (a.w - z4.w);
  *(float4*)(q + (size_t)row * DBN + lane * 4) = qv;
  ushort4 qb4;
  qb4.x = f2b(qv.x); qb4.y = f2b(qv.y); qb4.z = f2b(qv.z); qb4.w = f2b(qv.w);
  *(ushort4*)(qb + (size_t)row * DBN + lane * 4) = qb4;
}

// flat f32 -> bf16 convert (n4 = elements/4)
__global__ __launch_bounds__(256) void conv_flat(
    const float* __restrict__ in, ushort* __restrict__ out, int n4)
{
  const int i = blockIdx.x * 256 + threadIdx.x;
  if (i >= n4) return;
  const float4 v = *(const float4*)(in + (size_t)i * 4);
  ushort4 o;
  o.x = f2b(v.x); o.y = f2b(v.y); o.z = f2b(v.z); o.w = f2b(v.w);
  *(ushort4*)(out + (size_t)i * 4) = o;
}

// transpose-convert: in [K][N] f32 -> out [N][K] bf16. grid (K/32, N/32).
__global__ __launch_bounds__(256) void convT(
    const float* __restrict__ in, ushort* __restrict__ out, int K, int N)
{
  __shared__ float t[32][33];
  const int k0 = blockIdx.x * 32, n0 = blockIdx.y * 32;
  const int tx = threadIdx.x & 31, ty = threadIdx.x >> 5;
  #pragma unroll
  for (int i = 0; i < 32; i += 8)
    t[ty + i][tx] = in[(size_t)(k0 + ty + i) * N + n0 + tx];
  __syncthreads();
  #pragma unroll
  for (int i = 0; i < 32; i += 8)
    out[(size_t)(n0 + ty + i) * K + k0 + tx] = f2b(t[tx][ty + i]);
}

// transpose + 3-way split: in [K][N] f32 -> 3 parts [N][K] bf16.
__global__ __launch_bounds__(256) void convT_split3(
    const float* __restrict__ in, ushort* __restrict__ o1,
    ushort* __restrict__ o2, ushort* __restrict__ o3, int K, int N)
{
  __shared__ float t[32][33];
  const int k0 = blockIdx.x * 32, n0 = blockIdx.y * 32;
  const int tx = threadIdx.x & 31, ty = threadIdx.x >> 5;
  #pragma unroll
  for (int i = 0; i < 32; i += 8)
    t[ty + i][tx] = in[(size_t)(k0 + ty + i) * N + n0 + tx];
  __syncthreads();
  #pragma unroll
  for (int i = 0; i < 32; i += 8) {
    const float v = t[tx][ty + i];
    ushort s1, s2, s3;
    split3(v, s1, s2, s3);
    const size_t o = (size_t)(n0 + ty + i) * K + k0 + tx;
    o1[o] = s1; o2[o] = s2; o3[o] = s3;
  }
}

// Commitment: 0.25 * mean over stages of per-stage mean squared residual.
__global__ __launch_bounds__(256) void commit_kernel(
    const float* __restrict__ parts, float* __restrict__ out)
{
  __shared__ float sm[256];
  float s = 0.f;
  for (int i = threadIdx.x; i < NQ * 4096; i += 256) s += parts[i];
  sm[threadIdx.x] = s;
  __syncthreads();
  for (int st = 128; st > 0; st >>= 1) {
    if (threadIdx.x < st) sm[threadIdx.x] += sm[threadIdx.x + st];
    __syncthreads();
  }
  if (threadIdx.x == 0)
    out[0] = 0.25f * sm[0] / (8.0f * 4194304.0f);
}

extern "C" void kernel_launch(void* const* d_in, const int* in_sizes, int n_in,
                              void* d_out, int out_size, void* d_ws, size_t ws_size,
                              hipStream_t stream) {
  (void)in_sizes; (void)n_in; (void)out_size; (void)ws_size;
  const float* x    = (const float*)d_in[0];
  const float* W_e1 = (const float*)d_in[1];
  const float* b_e1 = (const float*)d_in[2];
  const float* W_e2 = (const float*)d_in[3];
  const float* b_e2 = (const float*)d_in[4];
  const float* cb   = (const float*)d_in[5];
  const float* W_d1 = (const float*)d_in[6];
  const float* b_d1 = (const float*)d_in[7];
  const float* W_d2 = (const float*)d_in[8];
  const float* b_d2 = (const float*)d_in[9];

  float* out = (float*)d_out;
  float* z_out   = out + OFF_Z;
  float* q_out   = out + OFF_Q;
  float* idx_out = out + OFF_IDX;
  float* rec_out = out + OFF_REC;
  float* com_out = out + OFF_COM;

  // ws layout (88.2 MB total):
  //   floats: hidden[16.78M] | res[4.19M] | cnorm[8K] | closs[32K] | tail
  //   hidden region aliases (post-e2): Dmat fp16 | resb | cbb->qb
  //   res region start aliases We1T 3-part (dead before e2 writes res)
  float* ws      = (float*)d_ws;
  float* hidden  = ws;                                // [0, 16777216)
  float* res     = ws + 16777216;                     // 4,194,304
  float* cnorm   = ws + 20971520;                     // 8,192
  float* closs   = ws + 20979712;                     // 32,768
  ushort* wtail  = (ushort*)(ws + 21012480);
  ushort* We2T1  = wtail;                             // 262,144
  ushort* We2T2  = wtail + 262144;
  ushort* We2T3  = wtail + 524288;
  ushort* Wd1T   = wtail + 786432;                    // 262,144
  ushort* Wd2T   = wtail + 1048576;                   // 1,048,576 (end 2,097,152)

  ushort* resu   = (ushort*)res;                      // We1T: dead before e2
  ushort* We1T1  = resu;                              // 1,048,576
  ushort* We1T2  = resu + 1048576;
  ushort* We1T3  = resu + 2097152;                    // ends 3,145,728 (< 8.39M)

  ushort* hregion = (ushort*)d_ws;
  _Float16* Dmat = (_Float16*)hregion;                // [0, 16777216) halves
  ushort* resb   = hregion + 16777216;                // 4,194,304
  ushort* cbb    = hregion + 20971520;                // 2,097,152 (dead at qfix)
  ushort* qb     = hregion + 20971520;                // 4,194,304 (post-RVQ)
  ushort* hidb   = hregion;                           // decoder hidden (post-RVQ)

  // one-time prep: codebook norms + weight transposes/splits
  cnorm_kernel<<<2048, 256, 0, stream>>>(cb, cnorm);
  convT_split3<<<dim3(32, 32), 256, 0, stream>>>(W_e1, We1T1, We1T2, We1T3, DIN, DIN);
  convT_split3<<<dim3(32, 8),  256, 0, stream>>>(W_e2, We2T1, We2T2, We2T3, DIN, DBN);
  convT<<<dim3(8, 32),  256, 0, stream>>>(W_d1, Wd1T, DBN, DIN);
  convT<<<dim3(32, 32), 256, 0, stream>>>(W_d2, Wd2T, DIN, DIN);

  // encoder: fp32-accurate split-bf16 MFMA (6 products), A direct-from-global
  gemm6<true,  4, 0><<<dim3(128, 8), 256, 0, stream>>>(
      x, We1T1, We1T2, We1T3, b_e1, hidden, nullptr, nullptr, DIN, DIN);
  gemm6<false, 2, 1><<<dim3(128, 4), 256, 0, stream>>>(
      hidden, We2T1, We2T2, We2T3, b_e2, z_out, res, resb, DBN, DIN);

  // bf16 codebook copy for the screen (hidden region free now)
  conv_flat<<<2048, 256, 0, stream>>>(cb, cbb, 524288);

  // RVQ stages: bf16 MFMA screen + exact fp32 margin rescore
  for (int s = 0; s < NQ; ++s) {
    rvq_screen<<<dim3(128, 8), 256, 0, stream>>>(
        resb, cbb + (size_t)s * NCODE * DBN, cnorm + s * NCODE, Dmat);
    rvq_rescore<<<4096, 256, 0, stream>>>(
        Dmat, cb + (size_t)s * NCODE * DBN, cnorm + s * NCODE,
        res, resb, idx_out + (size_t)s * NROWS, closs + s * 4096);
  }

  // q_total gather + straight-through (fp32 exact) + bf16 copy for decoder
  qfix_gather<<<4096, 256, 0, stream>>>(z_out, idx_out, cb, q_out, qb);

  // decoder (bf16 MFMA)
  gemm_bf16<true,  false><<<dim3(128, 8), 256, 0, stream>>>(qb, Wd1T, b_d1, nullptr, hidb, DIN, DBN);
  gemm_bf16<false, true ><<<dim3(128, 8), 256, 0, stream>>>(hidb, Wd2T, b_d2, rec_out, nullptr, DIN, DIN);

  // commitment scalar
  commit_kernel<<<1, 256, 0, stream>>>(closs, com_out);
}

// Round 12
// 682.067 us; speedup vs baseline: 1.4243x; 1.4243x over previous
//
#include <hip/hip_runtime.h>
#include <math.h>

// Problem constants
#define NROWS 16384       // 8*2048
#define DIN   1024
#define DBN   256
#define NQ    8
#define NCODE 1024
#define MARGIN 2.0f

// Output layout (float32 flat)
#define OFF_Z    0
#define OFF_Q    4194304
#define OFF_IDX  8388608
#define OFF_REC  8519680
#define OFF_COM  25296896

typedef __attribute__((ext_vector_type(8))) short short8v;
typedef __attribute__((ext_vector_type(4))) float f32x4;

__device__ __forceinline__ float gelu_f(float x) {
  return 0.5f * x * (1.0f + erff(x * 0.70710678118654752440f));
}

__device__ __forceinline__ ushort f2b(float x) {
  unsigned u = __float_as_uint(x);
  unsigned r = u + 0x7FFF + ((u >> 16) & 1);
  return (ushort)(r >> 16);
}
__device__ __forceinline__ float b2f(ushort u) {
  return __uint_as_float((unsigned)u << 16);
}
// 3-way bf16 split, ROUND-to-nearest at every stage (R4/R6-proven):
// v = b1 + b2 + b3 + err, |err| <= ~2^-27 |v|. Truncating variants (R5,
// ~2^-25) flip near-tie argmins — NEVER weaken this.
__device__ __forceinline__ void split3(float v, ushort& s1, ushort& s2, ushort& s3) {
  s1 = f2b(v);
  const float r1 = v - b2f(s1);
  s2 = f2b(r1);
  const float r2 = r1 - b2f(s2);
  s3 = f2b(r2);
}

// ---------------------------------------------------------------------------
// fp32-accurate GEMM on MFMA via 3-way bf16 split (6 products):
// C = act(A@B^T + bias). A fp32 [M][K], split on the fly during staging.
// B pre-split into 3 bf16 parts [N][K]. 128xBN tile (BN=NB*32), BK=32,
// 4 waves (2x2). LDS rows are 192 B (XOR (row&7)<<4): conflict-free reads.
//
// RACE FIX (R12): OUT==1 no longer writes a bf16 copy. The old fused
// Ob=resb write aliased floats [8.39M,10.49M) INSIDE the hidden buffer
// that e2 concurrently READS as its A operand — block epilogues corrupted
// other blocks' A-tiles, scheduling-dependently (flaky R9/R10/R11 fails).
// The bf16 conversion is now a separate kernel AFTER e2 (kernel boundary
// = synchronization). Do not re-fuse without moving resb out of hidden.
// ---------------------------------------------------------------------------
template<bool GELU, int NB, int OUT>
__global__ __launch_bounds__(256) void gemm6(
    const float* __restrict__ Af,
    const ushort* __restrict__ B1, const ushort* __restrict__ B2,
    const ushort* __restrict__ B3,
    const float* __restrict__ bias,
    float* __restrict__ C0, float* __restrict__ C1,
    int N, int K)
{
  constexpr int BN = NB * 32;
  __shared__ char lds[24576 + BN * 192];
  char* ldsA = lds;                 // [128][96] bf16 (192B rows)
  char* ldsB = lds + 24576;         // [BN][96]
  const int tid = threadIdx.x;
  const int bm = blockIdx.x * 128;
  const int bn = blockIdx.y * BN;
  const int lane = tid & 63;
  const int wid = tid >> 6;
  const int wr = wid >> 1, wc = wid & 1;

  const int srow = tid >> 1, skh = tid & 1;   // A staging: 2 threads/row
  const float* Ap = Af + (size_t)(bm + srow) * K + skh * 16;
  const int abase = srow * 192;
  const int aswz = (srow & 7) << 4;

  f32x4 acc[4][NB];
  #pragma unroll
  for (int m = 0; m < 4; ++m)
    #pragma unroll
    for (int n = 0; n < NB; ++n) acc[m][n] = (f32x4)0.f;

  union U8 { ushort u[8]; short8v v; };

  const int nt = K >> 5;
  for (int t = 0; t < nt; ++t) {
    const int k0 = t << 5;
    __syncthreads();
    // ---- A: load 16 fp32, 3-way split, 16B LDS writes ----
    float av[16];
    *(float4*)&av[0]  = *(const float4*)(Ap + k0);
    *(float4*)&av[4]  = *(const float4*)(Ap + k0 + 4);
    *(float4*)&av[8]  = *(const float4*)(Ap + k0 + 8);
    *(float4*)&av[12] = *(const float4*)(Ap + k0 + 12);
    U8 p1[2], p2[2], p3[2];
    #pragma unroll
    for (int i = 0; i < 16; ++i) {
      ushort s1, s2, s3;
      split3(av[i], s1, s2, s3);
      p1[i >> 3].u[i & 7] = s1;
      p2[i >> 3].u[i & 7] = s2;
      p3[i >> 3].u[i & 7] = s3;
    }
    #pragma unroll
    for (int h2 = 0; h2 < 2; ++h2) {
      const int kb = skh * 32 + h2 * 16;
      *(short8v*)(ldsA + ((abase + 0   + kb) ^ aswz)) = p1[h2].v;
      *(short8v*)(ldsA + ((abase + 64  + kb) ^ aswz)) = p2[h2].v;
      *(short8v*)(ldsA + ((abase + 128 + kb) ^ aswz)) = p3[h2].v;
    }
    // ---- B: pre-split parts, straight uint4 copies ----
    if (NB == 4) {
      const int br = tid >> 1, bk = tid & 1;
      const size_t g = (size_t)(bn + br) * K + k0 + bk * 16;
      const int bb = br * 192, bswz = (br & 7) << 4;
      #pragma unroll
      for (int h2 = 0; h2 < 2; ++h2) {
        const int kb = bk * 32 + h2 * 16;
        *(uint4*)(ldsB + ((bb + 0   + kb) ^ bswz)) = *(const uint4*)(B1 + g + h2 * 8);
        *(uint4*)(ldsB + ((bb + 64  + kb) ^ bswz)) = *(const uint4*)(B2 + g + h2 * 8);
        *(uint4*)(ldsB + ((bb + 128 + kb) ^ bswz)) = *(const uint4*)(B3 + g + h2 * 8);
      }
    } else {
      const int br = tid >> 2, bk = tid & 3;
      const size_t g = (size_t)(bn + br) * K + k0 + bk * 8;
      const int bb = br * 192, bswz = (br & 7) << 4;
      const int kb = bk * 16;
      *(uint4*)(ldsB + ((bb + 0   + kb) ^ bswz)) = *(const uint4*)(B1 + g);
      *(uint4*)(ldsB + ((bb + 64  + kb) ^ bswz)) = *(const uint4*)(B2 + g);
      *(uint4*)(ldsB + ((bb + 128 + kb) ^ bswz)) = *(const uint4*)(B3 + g);
    }
    __syncthreads();

    // ---- fragments + 6-product MFMA ----
    const int kq = (lane >> 4) << 4;
    short8v a1[4], a2[4], a3[4], b1v[NB], b2v[NB], b3v[NB];
    #pragma unroll
    for (int m = 0; m < 4; ++m) {
      const int row = wr * 64 + m * 16 + (lane & 15);
      const int base = row * 192, swz = (row & 7) << 4;
      a1[m] = *(const short8v*)(ldsA + ((base + 0   + kq) ^ swz));
      a2[m] = *(const short8v*)(ldsA + ((base + 64  + kq) ^ swz));
      a3[m] = *(const short8v*)(ldsA + ((base + 128 + kq) ^ swz));
    }
    #pragma unroll
    for (int n = 0; n < NB; ++n) {
      const int row = wc * (NB * 16) + n * 16 + (lane & 15);
      const int base = row * 192, swz = (row & 7) << 4;
      b1v[n] = *(const short8v*)(ldsB + ((base + 0   + kq) ^ swz));
      b2v[n] = *(const short8v*)(ldsB + ((base + 64  + kq) ^ swz));
      b3v[n] = *(const short8v*)(ldsB + ((base + 128 + kq) ^ swz));
    }
    #pragma unroll
    for (int m = 0; m < 4; ++m)
      #pragma unroll
      for (int n = 0; n < NB; ++n) {
        f32x4 a = acc[m][n];
        a = __builtin_amdgcn_mfma_f32_16x16x32_bf16(a3[m], b1v[n], a, 0, 0, 0);
        a = __builtin_amdgcn_mfma_f32_16x16x32_bf16(a1[m], b3v[n], a, 0, 0, 0);
        a = __builtin_amdgcn_mfma_f32_16x16x32_bf16(a2[m], b2v[n], a, 0, 0, 0);
        a = __builtin_amdgcn_mfma_f32_16x16x32_bf16(a2[m], b1v[n], a, 0, 0, 0);
        a = __builtin_amdgcn_mfma_f32_16x16x32_bf16(a1[m], b2v[n], a, 0, 0, 0);
        a = __builtin_amdgcn_mfma_f32_16x16x32_bf16(a1[m], b1v[n], a, 0, 0, 0);
        acc[m][n] = a;
      }
  }

  #pragma unroll
  for (int n = 0; n < NB; ++n) {
    const int col = bn + wc * (NB * 16) + n * 16 + (lane & 15);
    const float bb = bias[col];
    #pragma unroll
    for (int m = 0; m < 4; ++m) {
      const int row0 = bm + wr * 64 + m * 16 + ((lane >> 4) << 2);
      #pragma unroll
      for (int r = 0; r < 4; ++r) {
        float v = acc[m][n][r] + bb;
        if (GELU) v = gelu_f(v);
        C0[(size_t)(row0 + r) * N + col] = v;
        if (OUT == 1) C1[(size_t)(row0 + r) * N + col] = v;
      }
    }
  }
}

// ---------------------------------------------------------------------------
// bf16 MFMA GEMM core (screen + decoder): 128x128 tile, BK=64, 4 waves.
// A [M][K] bf16 row-major, B [N][K] bf16 (transposed). XOR-swizzled LDS.
// ---------------------------------------------------------------------------
__device__ __forceinline__ void mm_core(
    const ushort* __restrict__ A, const ushort* __restrict__ B,
    int K, int bm, int bn, char* lds, f32x4 acc[4][4])
{
  char* ldsA = lds;
  char* ldsB = lds + 16384;
  const int tid = threadIdx.x;
  const int lane = tid & 63;
  const int wid = tid >> 6;
  const int wr = wid >> 1, wc = wid & 1;

  #pragma unroll
  for (int m = 0; m < 4; ++m)
    #pragma unroll
    for (int n = 0; n < 4; ++n) acc[m][n] = (f32x4)0.f;

  const int nt = K >> 6;
  for (int t = 0; t < nt; ++t) {
    const int k0 = t << 6;
    __syncthreads();
    #pragma unroll
    for (int c = 0; c < 4; ++c) {
      const int id = c * 256 + tid;
      const int row = id >> 3, k8 = id & 7;
      const uint4 va = *(const uint4*)(A + (size_t)(bm + row) * K + k0 + k8 * 8);
      const uint4 vb = *(const uint4*)(B + (size_t)(bn + row) * K + k0 + k8 * 8);
      const int off = (row * 128 + k8 * 16) ^ ((row & 7) << 4);
      *(uint4*)(ldsA + off) = va;
      *(uint4*)(ldsB + off) = vb;
    }
    __syncthreads();
    #pragma unroll
    for (int kk = 0; kk < 2; ++kk) {
      short8v af[4], bfr[4];
      #pragma unroll
      for (int m = 0; m < 4; ++m) {
        const int row = wr * 64 + m * 16 + (lane & 15);
        af[m] = *(const short8v*)(ldsA +
            ((row * 128 + kk * 64 + ((lane >> 4) << 4)) ^ ((row & 7) << 4)));
      }
      #pragma unroll
      for (int n = 0; n < 4; ++n) {
        const int row = wc * 64 + n * 16 + (lane & 15);
        bfr[n] = *(const short8v*)(ldsB +
            ((row * 128 + kk * 64 + ((lane >> 4) << 4)) ^ ((row & 7) << 4)));
      }
      #pragma unroll
      for (int m = 0; m < 4; ++m)
        #pragma unroll
        for (int n = 0; n < 4; ++n)
          acc[m][n] = __builtin_amdgcn_mfma_f32_16x16x32_bf16(
              af[m], bfr[n], acc[m][n], 0, 0, 0);
    }
  }
}

// RVQ screen: approx d2 = cnorm - 2*(res.c) in bf16 MFMA -> fp16 matrix D.
__global__ __launch_bounds__(256) void rvq_screen(
    const ushort* __restrict__ resb, const ushort* __restrict__ cbb,
    const float* __restrict__ cnorm, _Float16* __restrict__ D)
{
  __shared__ char lds[32768];
  f32x4 acc[4][4];
  const int bm = blockIdx.x * 128, bn = blockIdx.y * 128;
  mm_core(resb, cbb, DBN, bm, bn, lds, acc);
  const int lane = threadIdx.x & 63;
  const int wid = threadIdx.x >> 6;
  const int wr = wid >> 1, wc = wid & 1;
  #pragma unroll
  for (int n = 0; n < 4; ++n) {
    const int col = bn + wc * 64 + n * 16 + (lane & 15);
    const float cn = cnorm[col];
    #pragma unroll
    for (int m = 0; m < 4; ++m) {
      const int row0 = bm + wr * 64 + m * 16 + ((lane >> 4) << 2);
      #pragma unroll
      for (int r = 0; r < 4; ++r)
        D[(size_t)(row0 + r) * NCODE + col] = (_Float16)(cn - 2.0f * acc[m][n][r]);
    }
  }
}

// Decoder bf16 GEMM: C = act(A@Bt^T + bias); fp32 or bf16 output.
template<bool GELU, bool OUTF>
__global__ __launch_bounds__(256) void gemm_bf16(
    const ushort* __restrict__ A, const ushort* __restrict__ Bt,
    const float* __restrict__ bias, float* __restrict__ Cf,
    ushort* __restrict__ Cb, int N, int K)
{
  __shared__ char lds[32768];
  f32x4 acc[4][4];
  const int bm = blockIdx.x * 128, bn = blockIdx.y * 128;
  mm_core(A, Bt, K, bm, bn, lds, acc);
  const int lane = threadIdx.x & 63;
  const int wid = threadIdx.x >> 6;
  const int wr = wid >> 1, wc = wid & 1;
  #pragma unroll
  for (int n = 0; n < 4; ++n) {
    const int col = bn + wc * 64 + n * 16 + (lane & 15);
    const float bb = bias[col];
    #pragma unroll
    for (int m = 0; m < 4; ++m) {
      const int row0 = bm + wr * 64 + m * 16 + ((lane >> 4) << 2);
      #pragma unroll
      for (int r = 0; r < 4; ++r) {
        float v = acc[m][n][r] + bb;
        if (GELU) v = gelu_f(v);
        if (OUTF) Cf[(size_t)(row0 + r) * N + col] = v;
        else      Cb[(size_t)(row0 + r) * N + col] = f2b(v);
      }
    }
  }
}

// Codebook squared norms (exact fp32): one wave per code row.
__global__ __launch_bounds__(256) void cnorm_kernel(
    const float* __restrict__ cb, float* __restrict__ cnorm)
{
  const int code = blockIdx.x * 4 + (threadIdx.x >> 6);
  const int lane = threadIdx.x & 63;
  float4 v = *(const float4*)(cb + (size_t)code * DBN + lane * 4);
  float s = v.x * v.x + v.y * v.y + v.z * v.z + v.w * v.w;
  #pragma unroll
  for (int o = 32; o > 0; o >>= 1) s += __shfl_down(s, o, 64);
  if (lane == 0) cnorm[code] = s;
}

// ---------------------------------------------------------------------------
// RVQ rescore + finalize (one wave per row): candidates within MARGIN of the
// approx min, exact fp32 rescore (lowest-index tie-break), residual update.
// ---------------------------------------------------------------------------
__global__ __launch_bounds__(256) void rvq_rescore(
    const _Float16* __restrict__ D, const float* __restrict__ cb_s,
    const float* __restrict__ cnorm_s,
    float* __restrict__ res, ushort* __restrict__ resb,
    float* __restrict__ idx_out, float* __restrict__ closs_part)
{
  __shared__ int cnt[4];
  __shared__ ushort cand[4][128];
  __shared__ float wsum[4];
  const int w = threadIdx.x >> 6, lane = threadIdx.x & 63;
  const int row = blockIdx.x * 4 + w;
  if (lane == 0) cnt[w] = 0;

  union H8 { uint4 u; _Float16 h[8]; };
  const _Float16* Dr = D + (size_t)row * NCODE + lane * 16;
  H8 a0, a1;
  a0.u = *(const uint4*)(Dr);
  a1.u = *(const uint4*)(Dr + 8);
  float dv[16];
  #pragma unroll
  for (int i = 0; i < 8; ++i) { dv[i] = (float)a0.h[i]; dv[8 + i] = (float)a1.h[i]; }

  float mn = dv[0];
  #pragma unroll
  for (int i = 1; i < 16; ++i) mn = fminf(mn, dv[i]);
  #pragma unroll
  for (int o = 32; o > 0; o >>= 1) mn = fminf(mn, __shfl_xor(mn, o, 64));
  const float thr = mn + MARGIN;

  #pragma unroll
  for (int i = 0; i < 16; ++i)
    if (dv[i] < thr) {
      int p = atomicAdd(&cnt[w], 1);
      if (p < 128) cand[w][p] = (ushort)(lane * 16 + i);
    }
  const int ncand = min(cnt[w], 128);

  const float4 r4 = *(const float4*)(res + (size_t)row * DBN + lane * 4);
  float bestv = INFINITY; int besti = 0x7fffffff;
  for (int c = 0; c < ncand; ++c) {
    const int code = cand[w][c];
    const float4 c4 = *(const float4*)(cb_s + (size_t)code * DBN + lane * 4);
    float d = r4.x * c4.x + r4.y * c4.y + r4.z * c4.z + r4.w * c4.w;
    #pragma unroll
    for (int o = 32; o > 0; o >>= 1) d += __shfl_xor(d, o, 64);
    const float ex = cnorm_s[code] - 2.0f * d;
    if (ex < bestv || (ex == bestv && code < besti)) { bestv = ex; besti = code; }
  }

  const float4 q4 = *(const float4*)(cb_s + (size_t)besti * DBN + lane * 4);
  float4 n4;
  n4.x = r4.x - q4.x; n4.y = r4.y - q4.y; n4.z = r4.z - q4.z; n4.w = r4.w - q4.w;
  *(float4*)(res + (size_t)row * DBN + lane * 4) = n4;
  ushort4 nb;
  nb.x = f2b(n4.x); nb.y = f2b(n4.y); nb.z = f2b(n4.z); nb.w = f2b(n4.w);
  *(ushort4*)(resb + (size_t)row * DBN + lane * 4) = nb;

  float s = n4.x * n4.x + n4.y * n4.y + n4.z * n4.z + n4.w * n4.w;
  #pragma unroll
  for (int o = 32; o > 0; o >>= 1) s += __shfl_xor(s, o, 64);
  if (lane == 0) { wsum[w] = s; idx_out[row] = (float)besti; }
  __syncthreads();
  if (threadIdx.x == 0)
    closs_part[blockIdx.x] = wsum[0] + wsum[1] + wsum[2] + wsum[3];
}

// q_total gather + straight-through: q = z + (sum_s cb[s][idx_s] - z).
__global__ __launch_bounds__(256) void qfix_gather(
    const float* __restrict__ z, const float* __restrict__ idxf,
    const float* __restrict__ cb, float* __restrict__ q, ushort* __restrict__ qb)
{
  const int w = threadIdx.x >> 6, lane = threadIdx.x & 63;
  const int row = blockIdx.x * 4 + w;
  float4 a; a.x = 0.f; a.y = 0.f; a.z = 0.f; a.w = 0.f;
  #pragma unroll
  for (int s = 0; s < NQ; ++s) {
    const int ix = (int)idxf[(size_t)s * NROWS + row];
    const float4 c4 = *(const float4*)(cb + ((size_t)s * NCODE + ix) * DBN + lane * 4);
    a.x += c4.x; a.y += c4.y; a.z += c4.z; a.w += c4.w;
  }
  const float4 z4 = *(const float4*)(z + (size_t)row * DBN + lane * 4);
  float4 qv;
  qv.x = z4.x + (a.x - z4.x); qv.y = z4.y + (a.y - z4.y);
  qv.z = z4.z + (a.z - z4.z); qv.w = z4.w + (a.w - z4.w);
  *(float4*)(q + (size_t)row * DBN + lane * 4) = qv;
  ushort4 qb4;
  qb4.x = f2b(qv.x); qb4.y = f2b(qv.y); qb4.z = f2b(qv.z); qb4.w = f2b(qv.w);
  *(ushort4*)(qb + (size_t)row * DBN + lane * 4) = qb4;
}

// flat f32 -> bf16 convert (n4 = elements/4)
__global__ __launch_bounds__(256) void conv_flat(
    const float* __restrict__ in, ushort* __restrict__ out, int n4)
{
  const int i = blockIdx.x * 256 + threadIdx.x;
  if (i >= n4) return;
  const float4 v = *(const float4*)(in + (size_t)i * 4);
  ushort4 o;
  o.x = f2b(v.x); o.y = f2b(v.y); o.z = f2b(v.z); o.w = f2b(v.w);
  *(ushort4*)(out + (size_t)i * 4) = o;
}

// transpose-convert: in [K][N] f32 -> out [N][K] bf16. grid (K/32, N/32).
__global__ __launch_bounds__(256) void convT(
    const float* __restrict__ in, ushort* __restrict__ out, int K, int N)
{
  __shared__ float t[32][33];
  const int k0 = blockIdx.x * 32, n0 = blockIdx.y * 32;
  const int tx = threadIdx.x & 31, ty = threadIdx.x >> 5;
  #pragma unroll
  for (int i = 0; i < 32; i += 8)
    t[ty + i][tx] = in[(size_t)(k0 + ty + i) * N + n0 + tx];
  __syncthreads();
  #pragma unroll
  for (int i = 0; i < 32; i += 8)
    out[(size_t)(n0 + ty + i) * K + k0 + tx] = f2b(t[tx][ty + i]);
}

// transpose + 3-way split: in [K][N] f32 -> 3 parts [N][K] bf16.
__global__ __launch_bounds__(256) void convT_split3(
    const float* __restrict__ in, ushort* __restrict__ o1,
    ushort* __restrict__ o2, ushort* __restrict__ o3, int K, int N)
{
  __shared__ float t[32][33];
  const int k0 = blockIdx.x * 32, n0 = blockIdx.y * 32;
  const int tx = threadIdx.x & 31, ty = threadIdx.x >> 5;
  #pragma unroll
  for (int i = 0; i < 32; i += 8)
    t[ty + i][tx] = in[(size_t)(k0 + ty + i) * N + n0 + tx];
  __syncthreads();
  #pragma unroll
  for (int i = 0; i < 32; i += 8) {
    const float v = t[tx][ty + i];
    ushort s1, s2, s3;
    split3(v, s1, s2, s3);
    const size_t o = (size_t)(n0 + ty + i) * K + k0 + tx;
    o1[o] = s1; o2[o] = s2; o3[o] = s3;
  }
}

// Commitment: 0.25 * mean over stages of per-stage mean squared residual.
__global__ __launch_bounds__(256) void commit_kernel(
    const float* __restrict__ parts, float* __restrict__ out)
{
  __shared__ float sm[256];
  float s = 0.f;
  for (int i = threadIdx.x; i < NQ * 4096; i += 256) s += parts[i];
  sm[threadIdx.x] = s;
  __syncthreads();
  for (int st = 128; st > 0; st >>= 1) {
    if (threadIdx.x < st) sm[threadIdx.x] += sm[threadIdx.x + st];
    __syncthreads();
  }
  if (threadIdx.x == 0)
    out[0] = 0.25f * sm[0] / (8.0f * 4194304.0f);
}

extern "C" void kernel_launch(void* const* d_in, const int* in_sizes, int n_in,
                              void* d_out, int out_size, void* d_ws, size_t ws_size,
                              hipStream_t stream) {
  (void)in_sizes; (void)n_in; (void)out_size; (void)ws_size;
  const float* x    = (const float*)d_in[0];
  const float* W_e1 = (const float*)d_in[1];
  const float* b_e1 = (const float*)d_in[2];
  const float* W_e2 = (const float*)d_in[3];
  const float* b_e2 = (const float*)d_in[4];
  const float* cb   = (const float*)d_in[5];
  const float* W_d1 = (const float*)d_in[6];
  const float* b_d1 = (const float*)d_in[7];
  const float* W_d2 = (const float*)d_in[8];
  const float* b_d2 = (const float*)d_in[9];

  float* out = (float*)d_out;
  float* z_out   = out + OFF_Z;
  float* q_out   = out + OFF_Q;
  float* idx_out = out + OFF_IDX;
  float* rec_out = out + OFF_REC;
  float* com_out = out + OFF_COM;

  // ws layout (88.2 MB total):
  //   floats: hidden[16.78M] | res[4.19M] | cnorm[8K] | closs[32K] | tail
  //   hidden region aliases (post-e2): Dmat fp16 | resb | cbb->qb
  //   res region start aliases We1T 3-part (dead before e2 writes res)
  //   NOTE: resb/qb/cbb live INSIDE the hidden float region — they may only
  //   be written by kernels launched AFTER the last reader of hidden (e2).
  float* ws      = (float*)d_ws;
  float* hidden  = ws;                                // [0, 16777216)
  float* res     = ws + 16777216;                     // 4,194,304
  float* cnorm   = ws + 20971520;                     // 8,192
  float* closs   = ws + 20979712;                     // 32,768
  ushort* wtail  = (ushort*)(ws + 21012480);
  ushort* We2T1  = wtail;                             // 262,144
  ushort* We2T2  = wtail + 262144;
  ushort* We2T3  = wtail + 524288;
  ushort* Wd1T   = wtail + 786432;                    // 262,144
  ushort* Wd2T   = wtail + 1048576;                   // 1,048,576 (end 2,097,152)

  ushort* resu   = (ushort*)res;                      // We1T: dead before e2
  ushort* We1T1  = resu;                              // 1,048,576
  ushort* We1T2  = resu + 1048576;
  ushort* We1T3  = resu + 2097152;                    // ends 3,145,728 (< 8.39M)

  ushort* hregion = (ushort*)d_ws;
  _Float16* Dmat = (_Float16*)hregion;                // [0, 16777216) halves
  ushort* resb   = hregion + 16777216;                // 4,194,304
  ushort* cbb    = hregion + 20971520;                // 2,097,152 (dead at qfix)
  ushort* qb     = hregion + 20971520;                // 4,194,304 (post-RVQ)
  ushort* hidb   = hregion;                           // decoder hidden (post-RVQ)

  // one-time prep: codebook norms + weight transposes/splits
  cnorm_kernel<<<2048, 256, 0, stream>>>(cb, cnorm);
  convT_split3<<<dim3(32, 32), 256, 0, stream>>>(W_e1, We1T1, We1T2, We1T3, DIN, DIN);
  convT_split3<<<dim3(32, 8),  256, 0, stream>>>(W_e2, We2T1, We2T2, We2T3, DIN, DBN);
  convT<<<dim3(8, 32),  256, 0, stream>>>(W_d1, Wd1T, DBN, DIN);
  convT<<<dim3(32, 32), 256, 0, stream>>>(W_d2, Wd2T, DIN, DIN);

  // encoder: fp32-accurate split-bf16 MFMA (6 products)
  gemm6<true,  4, 0><<<dim3(128, 8), 256, 0, stream>>>(
      x, We1T1, We1T2, We1T3, b_e1, hidden, nullptr, DIN, DIN);
  gemm6<false, 2, 1><<<dim3(128, 4), 256, 0, stream>>>(
      hidden, We2T1, We2T2, We2T3, b_e2, z_out, res, DBN, DIN);

  // bf16 conversions AFTER e2 (race fix: resb aliases hidden, which e2 reads)
  conv_flat<<<4096, 256, 0, stream>>>(res, resb, 1048576);
  conv_flat<<<2048, 256, 0, stream>>>(cb, cbb, 524288);

  // RVQ stages: bf16 MFMA screen + exact fp32 margin rescore
  for (int s = 0; s < NQ; ++s) {
    rvq_screen<<<dim3(128, 8), 256, 0, stream>>>(
        resb, cbb + (size_t)s * NCODE * DBN, cnorm + s * NCODE, Dmat);
    rvq_rescore<<<4096, 256, 0, stream>>>(
        Dmat, cb + (size_t)s * NCODE * DBN, cnorm + s * NCODE,
        res, resb, idx_out + (size_t)s * NROWS, closs + s * 4096);
  }

  // q_total gather + straight-through (fp32 exact) + bf16 copy for decoder
  qfix_gather<<<4096, 256, 0, stream>>>(z_out, idx_out, cb, q_out, qb);

  // decoder (bf16 MFMA)
  gemm_bf16<true,  false><<<dim3(128, 8), 256, 0, stream>>>(qb, Wd1T, b_d1, nullptr, hidb, DIN, DBN);
  gemm_bf16<false, true ><<<dim3(128, 8), 256, 0, stream>>>(hidb, Wd2T, b_d2, rec_out, nullptr, DIN, DIN);

  // commitment scalar
  commit_kernel<<<1, 256, 0, stream>>>(closs, com_out);
}